// Round 12
// baseline (175.442 us; speedup 1.0000x reference)
//
#include <hip/hip_runtime.h>

constexpr int NPAIR = 780;

// ---- fused-kernel LDS layout (floats) ----
constexpr int OFF_ZT = 0;            // Zt[32][40] stride 40            1280
constexpr int OFF_A  = 1280;         // h[40][132]=5280 | Ut[3][32][40]=3840
constexpr int UTP    = 1280;         // Ut plane stride
constexpr int OFF_BT = 5120;         // bilT[5][780]=3900
constexpr int SH_TOT = 9020;         // 36080 B -> 4 blocks/CU

// ---- packed fp32 helpers (VOP3P). gfx950 packed-f32 set: fma/mul/add/mov ONLY
// (no packed max — use scalar v_max_f32 on halves).
// ISA rule: every pk source is a 64-bit register PAIR; op_sel picks halves.
typedef float v2f __attribute__((ext_vector_type(2)));
typedef float v4f __attribute__((ext_vector_type(4)));
union V4 { v4f v; v2f h[2]; float f[4]; };

// acc.k += s2.lo * b.k  (broadcast LOW half of s2)   [bit-exact 2xFMA]
__device__ __forceinline__ void pk_fma_lo(v2f& acc, v2f s2, v2f b) {
  asm("v_pk_fma_f32 %0, %1, %2, %0 op_sel:[0,0,0] op_sel_hi:[0,1,1]"
      : "+v"(acc) : "v"(s2), "v"(b));
}
// acc.k += s2.hi * b.k  (broadcast HIGH half of s2)
__device__ __forceinline__ void pk_fma_hi(v2f& acc, v2f s2, v2f b) {
  asm("v_pk_fma_f32 %0, %1, %2, %0 op_sel:[1,0,0] op_sel_hi:[1,1,1]"
      : "+v"(acc) : "v"(s2), "v"(b));
}
// acc.k += a.k * b.k, b from SGPR pair (uniform weights)
__device__ __forceinline__ void pk_fma_vs(v2f& acc, v2f a, v2f b) {
  asm("v_pk_fma_f32 %0, %1, %2, %0 op_sel:[0,0,0] op_sel_hi:[1,1,1]"
      : "+v"(acc) : "v"(a), "s"(b));
}
__device__ __forceinline__ v2f pk_add(v2f a, v2f b) {
  v2f d; asm("v_pk_add_f32 %0, %1, %2" : "=v"(d) : "v"(a), "v"(b)); return d;
}
// relu(a+b) with scalar maxes (no packed max on gfx950)
__device__ __forceinline__ v2f pk_addrelu(v2f a, v2f b) {
  v2f s = pk_add(a, b);
  v2f d; d.x = fmaxf(s.x, 0.f); d.y = fmaxf(s.y, 0.f);
  return d;
}

// =================== prep: cluster head + wsym + sigma + head-weight table ===================
__global__ __launch_bounds__(256) void prep_kernel(
    const float* __restrict__ eta,
    const float* __restrict__ cW1, const float* __restrict__ cb1,
    const float* __restrict__ cW2, const float* __restrict__ cb2,
    const float* __restrict__ cWs, const float* __restrict__ cbs,
    const float* __restrict__ bond, const float* __restrict__ lsig,
    const float* __restrict__ bW1, const float* __restrict__ bb1,
    const float* __restrict__ bW2, const float* __restrict__ bb2,
    const float* __restrict__ bWs, const float* __restrict__ bbs,
    float* __restrict__ log_pi, float* __restrict__ wsym,
    float* __restrict__ sigma, float* __restrict__ hwg)
{
  if (blockIdx.x < 256) {
    const int lane = threadIdx.x & 63, wid = threadIdx.x >> 6;
    const int row = blockIdx.x * 4 + wid;
    __shared__ __align__(16) float etas[4][64];
    __shared__ __align__(16) float hs[4][128];
    etas[wid][lane] = eta[row * 64 + lane];
    __syncthreads();
    float a0 = cb1[lane], a1 = cb1[lane + 64];
    for (int d = 0; d < 64; ++d) {
      float ed = etas[wid][d];
      a0 += ed * cW1[d * 128 + lane];
      a1 += ed * cW1[d * 128 + lane + 64];
    }
    hs[wid][lane] = fmaxf(a0, 0.f);
    hs[wid][lane + 64] = fmaxf(a1, 0.f);
    __syncthreads();
    if (lane < 32) {
      float x = cb2[lane] + cbs[lane];
      for (int j = 0; j < 128; ++j) x += hs[wid][j] * cW2[j * 32 + lane];
      for (int d = 0; d < 64; ++d) x += etas[wid][d] * cWs[d * 32 + lane];
      float m = x;
      for (int off = 16; off; off >>= 1) m = fmaxf(m, __shfl_xor(m, off));
      float e = __expf(x - m);
      float s = e;
      for (int off = 16; off; off >>= 1) s += __shfl_xor(s, off);
      log_pi[row * 32 + lane] = (x - m) - __logf(s);
    }
  } else {
    const int e = (blockIdx.x - 256) * 256 + threadIdx.x;
    if (e < 5120) {
      const int t = e >> 10, r = e & 1023, c = r >> 5, d = r & 31;
      wsym[e] = 0.5f * (bond[e] + bond[t * 1024 + d * 32 + c]);
    } else if (e < 6144) {
      const int q = e - 5120;
      sigma[q] = __expf(fminf(fmaxf(lsig[q], -20.f), 30.f));
    } else if (e < 6888) {
      // hwg: w1h[320]@0, b1h[64]@320, w2t[320]@384 (bW2^T), b2h[5]@704, wsh[25]@709, bsh[5]@734
      const int idx = e - 6144;
      float v;
      if (idx < 320) v = bW1[idx];
      else if (idx < 384) v = bb1[idx - 320];
      else if (idx < 704) { int qq = idx - 384; int t2 = qq >> 6, j = qq & 63; v = bW2[j * 5 + t2]; }
      else if (idx < 709) v = bb2[idx - 704];
      else if (idx < 734) v = bWs[idx - 709];
      else v = bbs[idx - 734];
      hwg[idx] = v;
    }
  }
}

// =================== fused per-molecule kernel, 256 threads ===================
// R19 = R6 (best known, 63.6us; R11's P3/P8 pk-trio reverted as measured-negative)
//   + P1 z_noise-load hoist (independent of argmax chain; verified R7/R11)
//   + P8 tail assigned to wave (m>>8)&3 so co-resident blocks' tail waves land
//     on different SIMDs (was: always wave 0 -> 4x tail pileup on SIMD 0)
__global__ __launch_bounds__(256, 4) void fused_kernel(
    const float* __restrict__ log_pi, const float* __restrict__ gumbel,
    const float* __restrict__ z_noise,
    const float* __restrict__ means, const float* __restrict__ sigma,
    const float* __restrict__ aW1, const float* __restrict__ ab1,
    const float* __restrict__ aW2, const float* __restrict__ ab2,
    const float* __restrict__ aWs, const float* __restrict__ abs_,
    const float* __restrict__ wsym, const float* __restrict__ hwg,
    float* __restrict__ atom_out, float* __restrict__ edge_out)
{
  __shared__ __align__(16) float S[SH_TOT];
  const int tid = threadIdx.x;
  const int lane = tid & 63, wid = tid >> 6;
  const int m = blockIdx.x;

  // ---------- phase 1: z sample, 40n x 4sub = 160 threads spread over all waves ----------
  if (lane < 40) {
    const int n = wid * 10 + (lane >> 2);     // 10 nodes per wave
    const int sub = lane & 3;                 // 4 lanes cooperate per node
    const int c0 = sub * 8;                   // 8 channels each
    const int n_glb = m * 40 + n;
    const float4* lp4 = (const float4*)(log_pi + m * 32 + c0);
    const float4* g4  = (const float4*)(gumbel + (size_t)n_glb * 32 + c0);
    const float4* zn4 = (const float4*)(z_noise + (size_t)n_glb * 32 + c0);
    float4 zn0 = zn4[0], zn1 = zn4[1];        // hoisted: independent of argmax
    float vals[8];
    {
      float4 a = lp4[0], b = g4[0];
      vals[0] = a.x + b.x; vals[1] = a.y + b.y; vals[2] = a.z + b.z; vals[3] = a.w + b.w;
    }
    {
      float4 a = lp4[1], b = g4[1];
      vals[4] = a.x + b.x; vals[5] = a.y + b.y; vals[6] = a.z + b.z; vals[7] = a.w + b.w;
    }
    int kb = c0; float vb = vals[0];
    #pragma unroll
    for (int q = 1; q < 8; ++q)
      if (vals[q] > vb) { vb = vals[q]; kb = c0 + q; }   // first-index within thread
    // 4-lane argmax reduce, first-index tie-break (smaller channel wins on equal value)
    #pragma unroll
    for (int off = 1; off <= 2; off <<= 1) {
      float vo = __shfl_xor(vb, off);
      int   ko = __shfl_xor(kb, off);
      if (vo > vb || (vo == vb && ko < kb)) { vb = vo; kb = ko; }
    }
    const float4* mk4 = (const float4*)(means + kb * 32 + c0);
    const float4* sg4 = (const float4*)(sigma + kb * 32 + c0);
    {
      float4 mk = mk4[0], sg = sg4[0];
      S[OFF_ZT + (c0    ) * 40 + n] = zn0.x * sg.x + mk.x;
      S[OFF_ZT + (c0 + 1) * 40 + n] = zn0.y * sg.y + mk.y;
      S[OFF_ZT + (c0 + 2) * 40 + n] = zn0.z * sg.z + mk.z;
      S[OFF_ZT + (c0 + 3) * 40 + n] = zn0.w * sg.w + mk.w;
    }
    {
      float4 mk = mk4[1], sg = sg4[1];
      S[OFF_ZT + (c0 + 4) * 40 + n] = zn1.x * sg.x + mk.x;
      S[OFF_ZT + (c0 + 5) * 40 + n] = zn1.y * sg.y + mk.y;
      S[OFF_ZT + (c0 + 6) * 40 + n] = zn1.z * sg.z + mk.z;
      S[OFF_ZT + (c0 + 7) * 40 + n] = zn1.w * sg.w + mk.w;
    }
  }
  __syncthreads();

  // ---------- phase 2: atom-h, 4n x 4j tiles -> h[n][j] row-major (stride 132) ----------
  {
    for (int u = tid; u < 320; u += 256) {
      const int ng = u >> 5, jg = u & 31;
      const int n0 = ng * 4, j0 = jg * 4;
      v2f acc[4][2];
      #pragma unroll
      for (int a = 0; a < 4; ++a) { acc[a][0] = (v2f){0.f,0.f}; acc[a][1] = (v2f){0.f,0.f}; }
      #pragma unroll 8
      for (int c = 0; c < 32; ++c) {
        V4 zv; zv.v = *(const v4f*)&S[OFF_ZT + c * 40 + n0];
        V4 wv; wv.v = *(const v4f*)(aW1 + c * 128 + j0);
        pk_fma_lo(acc[0][0], zv.h[0], wv.h[0]); pk_fma_lo(acc[0][1], zv.h[0], wv.h[1]);
        pk_fma_hi(acc[1][0], zv.h[0], wv.h[0]); pk_fma_hi(acc[1][1], zv.h[0], wv.h[1]);
        pk_fma_lo(acc[2][0], zv.h[1], wv.h[0]); pk_fma_lo(acc[2][1], zv.h[1], wv.h[1]);
        pk_fma_hi(acc[3][0], zv.h[1], wv.h[0]); pk_fma_hi(acc[3][1], zv.h[1], wv.h[1]);
      }
      V4 bv; bv.v = *(const v4f*)(ab1 + j0);
      #pragma unroll
      for (int a = 0; a < 4; ++a) {
        V4 hv;
        hv.h[0] = pk_addrelu(acc[a][0], bv.h[0]);
        hv.h[1] = pk_addrelu(acc[a][1], bv.h[1]);
        *(v4f*)&S[OFF_A + (n0 + a) * 132 + j0] = hv.v;   // unit-stride b128 writes
      }
    }
  }
  __syncthreads();

  // ---------- phase 3: atom-out, thread = (n, kpair) ----------
  if (tid < 200) {
    const int n = tid / 5, kp = tid - (tid / 5) * 5, k0 = kp * 2;
    float a0 = ab2[k0] + abs_[k0];
    float a1 = ab2[k0 + 1] + abs_[k0 + 1];
    #pragma unroll 8
    for (int c = 0; c < 32; ++c) {
      float zc = S[OFF_ZT + c * 40 + n];
      float2 w = *(const float2*)(aWs + c * 10 + k0);
      a0 += zc * w.x; a1 += zc * w.y;
    }
    #pragma unroll 8
    for (int j = 0; j < 128; ++j) {
      float hv = S[OFF_A + n * 132 + j];
      float2 w = *(const float2*)(aW2 + j * 10 + k0);
      a0 += hv * w.x; a1 += hv * w.y;
    }
    *(float2*)(atom_out + (size_t)m * 400 + n * 10 + k0) = make_float2(a0, a1);
  }
  __syncthreads();   // h dead

  // ---------- phases 4-7: U + bilinear, two t-rounds ----------
  #pragma unroll
  for (int R = 0; R < 2; ++R) {
    const int tbase = (R == 0) ? 0 : 3;
    const int nplanes = (R == 0) ? 3 : 2;
    // U: units (tl, dg, ig) -> Ut[tl][d][i]
    if (tid < nplanes * 80) {
      const int tl = tid / 80, r = tid - tl * 80;
      const int dg = r / 10, ig = r - dg * 10;
      const int d0 = dg * 4, i0 = ig * 4;
      const float* wg = wsym + (tbase + tl) * 1024;
      v2f acc[4][2];   // [di][pair of i]
      #pragma unroll
      for (int a = 0; a < 4; ++a) { acc[a][0] = (v2f){0.f,0.f}; acc[a][1] = (v2f){0.f,0.f}; }
      #pragma unroll 8
      for (int c = 0; c < 32; ++c) {
        V4 zv; zv.v = *(const v4f*)&S[OFF_ZT + c * 40 + i0];
        V4 wv; wv.v = *(const v4f*)(wg + c * 32 + d0);
        pk_fma_lo(acc[0][0], wv.h[0], zv.h[0]); pk_fma_lo(acc[0][1], wv.h[0], zv.h[1]);
        pk_fma_hi(acc[1][0], wv.h[0], zv.h[0]); pk_fma_hi(acc[1][1], wv.h[0], zv.h[1]);
        pk_fma_lo(acc[2][0], wv.h[1], zv.h[0]); pk_fma_lo(acc[2][1], wv.h[1], zv.h[1]);
        pk_fma_hi(acc[3][0], wv.h[1], zv.h[0]); pk_fma_hi(acc[3][1], wv.h[1], zv.h[1]);
      }
      #pragma unroll
      for (int a = 0; a < 4; ++a) {
        V4 st; st.h[0] = acc[a][0]; st.h[1] = acc[a][1];
        *(v4f*)&S[OFF_A + tl * UTP + (d0 + a) * 40 + i0] = st.v;
      }
    }
    __syncthreads();

    // bilinear: units (tl, triangular 4i x 4j tile)
    if (tid < nplanes * 55) {
      const int tl = tid / 55;
      int q = tid - tl * 55;
      int ig = 0;
      while (q >= 10 - ig) { q -= 10 - ig; ++ig; }
      const int jg = ig + q;
      const int i0 = ig * 4, j0 = jg * 4;
      v2f acc[4][2];   // [i][pair of j]
      #pragma unroll
      for (int a = 0; a < 4; ++a) { acc[a][0] = (v2f){0.f,0.f}; acc[a][1] = (v2f){0.f,0.f}; }
      #pragma unroll 8
      for (int d = 0; d < 32; ++d) {
        V4 uv; uv.v = *(const v4f*)&S[OFF_A + tl * UTP + d * 40 + i0];
        V4 zv; zv.v = *(const v4f*)&S[OFF_ZT + d * 40 + j0];
        pk_fma_lo(acc[0][0], uv.h[0], zv.h[0]); pk_fma_lo(acc[0][1], uv.h[0], zv.h[1]);
        pk_fma_hi(acc[1][0], uv.h[0], zv.h[0]); pk_fma_hi(acc[1][1], uv.h[0], zv.h[1]);
        pk_fma_lo(acc[2][0], uv.h[1], zv.h[0]); pk_fma_lo(acc[2][1], uv.h[1], zv.h[1]);
        pk_fma_hi(acc[3][0], uv.h[1], zv.h[0]); pk_fma_hi(acc[3][1], uv.h[1], zv.h[1]);
      }
      const int tg = tbase + tl;
      #pragma unroll
      for (int a = 0; a < 4; ++a) {
        const int i = i0 + a;
        V4 row; row.h[0] = acc[a][0]; row.h[1] = acc[a][1];
        #pragma unroll
        for (int b = 0; b < 4; ++b) {
          const int j = j0 + b;
          if (i < j) {
            const int p = i * (79 - i) / 2 + (j - i - 1);
            S[OFF_BT + tg * 780 + p] = row.f[b];
          }
        }
      }
    }
    __syncthreads();
  }

  // ---------- phase 8: edge head; weights via UNIFORM global loads (s_load) ----------
  const float* w1h = hwg;
  const float* b1h = hwg + 320;
  const float* w2t = hwg + 384;
  const float* b2h = hwg + 704;
  const float* wsh = hwg + 709;
  const float* bsh = hwg + 734;

  // main: 3 unconditional slots (pairs 0..767) + guarded tail slot (768..779)
  // tail wave rotates with (m>>8)&3 so co-resident blocks' tails hit different SIMDs
  const bool htail = (wid == ((m >> 8) & 3)) && (lane < 12);
  const int ptail = 768 + lane;
  float bil5[3][5];
  v2f bil2[3][5];   // {v,v} broadcast pairs for pk src0
  v2f lg2[3][5];    // packed partial sums; .x seeded with the skip path
  #pragma unroll
  for (int s = 0; s < 3; ++s) {
    const int p = tid + (s << 8);
    #pragma unroll
    for (int t = 0; t < 5; ++t) {
      float v = S[OFF_BT + t * 780 + p];
      bil5[s][t] = v;
      bil2[s][t].x = v; bil2[s][t].y = v;
    }
    #pragma unroll
    for (int t2 = 0; t2 < 5; ++t2) {
      float a = b2h[t2] + bsh[t2];
      #pragma unroll
      for (int t = 0; t < 5; ++t) a += bil5[s][t] * wsh[t * 5 + t2];
      lg2[s][t2].x = a; lg2[s][t2].y = 0.f;
    }
  }
  float bil3[5], lg3[5];
  if (htail) {
    #pragma unroll
    for (int t = 0; t < 5; ++t) bil3[t] = S[OFF_BT + t * 780 + ptail];
    #pragma unroll
    for (int t2 = 0; t2 < 5; ++t2) {
      float a = b2h[t2] + bsh[t2];
      #pragma unroll
      for (int t = 0; t < 5; ++t) a += bil3[t] * wsh[t * 5 + t2];
      lg3[t2] = a;
    }
  }
  {
    for (int j4 = 0; j4 < 16; ++j4) {
      V4 bb; bb.v = *(const v4f*)(b1h + 4 * j4);       // uniform -> SGPR
      v2f h2[3][2];
      #pragma unroll
      for (int s = 0; s < 3; ++s) { h2[s][0] = bb.h[0]; h2[s][1] = bb.h[1]; }
      #pragma unroll
      for (int t = 0; t < 5; ++t) {
        V4 w1; w1.v = *(const v4f*)(w1h + t * 64 + 4 * j4);  // uniform -> SGPR
        #pragma unroll
        for (int s = 0; s < 3; ++s) {
          pk_fma_vs(h2[s][0], bil2[s][t], w1.h[0]);
          pk_fma_vs(h2[s][1], bil2[s][t], w1.h[1]);
        }
      }
      #pragma unroll
      for (int s = 0; s < 3; ++s) {
        h2[s][0].x = fmaxf(h2[s][0].x, 0.f); h2[s][0].y = fmaxf(h2[s][0].y, 0.f);
        h2[s][1].x = fmaxf(h2[s][1].x, 0.f); h2[s][1].y = fmaxf(h2[s][1].y, 0.f);
      }
      #pragma unroll
      for (int t2 = 0; t2 < 5; ++t2) {
        V4 w2; w2.v = *(const v4f*)(w2t + t2 * 64 + 4 * j4); // uniform -> SGPR
        #pragma unroll
        for (int s = 0; s < 3; ++s) {
          pk_fma_vs(lg2[s][t2], h2[s][0], w2.h[0]);
          pk_fma_vs(lg2[s][t2], h2[s][1], w2.h[1]);
        }
      }
      // tail slot: only the designated wave's lanes 0..11 enter (execz-skip elsewhere)
      if (htail) {
        float4 h3 = make_float4(bb.f[0], bb.f[1], bb.f[2], bb.f[3]);
        #pragma unroll
        for (int t = 0; t < 5; ++t) {
          const float* w1p = w1h + t * 64 + 4 * j4;
          float bt = bil3[t];
          h3.x += bt * w1p[0]; h3.y += bt * w1p[1]; h3.z += bt * w1p[2]; h3.w += bt * w1p[3];
        }
        h3.x = fmaxf(h3.x, 0.f); h3.y = fmaxf(h3.y, 0.f);
        h3.z = fmaxf(h3.z, 0.f); h3.w = fmaxf(h3.w, 0.f);
        #pragma unroll
        for (int t2 = 0; t2 < 5; ++t2) {
          const float* w2p = w2t + t2 * 64 + 4 * j4;
          lg3[t2] += h3.x * w2p[0] + h3.y * w2p[1] + h3.z * w2p[2] + h3.w * w2p[3];
        }
      }
    }
  }
  #pragma unroll
  for (int s = 0; s < 3; ++s) {
    const int p = tid + (s << 8);
    float lgv[5];
    #pragma unroll
    for (int t2 = 0; t2 < 5; ++t2) lgv[t2] = lg2[s][t2].x + lg2[s][t2].y;
    float mx = lgv[0];
    #pragma unroll
    for (int t2 = 1; t2 < 5; ++t2) mx = fmaxf(mx, lgv[t2]);
    float e[5], sum = 0.f;
    #pragma unroll
    for (int t2 = 0; t2 < 5; ++t2) { e[t2] = __expf(lgv[t2] - mx); sum += e[t2]; }
    float inv = 1.f / sum;
    float* outp = edge_out + ((size_t)m * NPAIR + p) * 5;
    #pragma unroll
    for (int t2 = 0; t2 < 5; ++t2) outp[t2] = e[t2] * inv;
  }
  if (htail) {
    float mx = lg3[0];
    #pragma unroll
    for (int t2 = 1; t2 < 5; ++t2) mx = fmaxf(mx, lg3[t2]);
    float e[5], sum = 0.f;
    #pragma unroll
    for (int t2 = 0; t2 < 5; ++t2) { e[t2] = __expf(lg3[t2] - mx); sum += e[t2]; }
    float inv = 1.f / sum;
    float* outp = edge_out + ((size_t)m * NPAIR + ptail) * 5;
    #pragma unroll
    for (int t2 = 0; t2 < 5; ++t2) outp[t2] = e[t2] * inv;
  }
}

extern "C" void kernel_launch(void* const* d_in, const int* in_sizes, int n_in,
                              void* d_out, int out_size, void* d_ws, size_t ws_size,
                              hipStream_t stream) {
  const float* eta    = (const float*)d_in[0];
  const float* gumbel = (const float*)d_in[1];
  const float* z_noise= (const float*)d_in[2];
  const float* cW1 = (const float*)d_in[3];
  const float* cb1 = (const float*)d_in[4];
  const float* cW2 = (const float*)d_in[5];
  const float* cb2 = (const float*)d_in[6];
  const float* cWs = (const float*)d_in[7];
  const float* cbs = (const float*)d_in[8];
  const float* means = (const float*)d_in[9];
  const float* lsig  = (const float*)d_in[10];
  const float* aW1 = (const float*)d_in[11];
  const float* ab1 = (const float*)d_in[12];
  const float* aW2 = (const float*)d_in[13];
  const float* ab2 = (const float*)d_in[14];
  const float* aWs = (const float*)d_in[15];
  const float* abs_= (const float*)d_in[16];
  const float* bond= (const float*)d_in[17];
  const float* bW1 = (const float*)d_in[18];
  const float* bb1 = (const float*)d_in[19];
  const float* bW2 = (const float*)d_in[20];
  const float* bb2 = (const float*)d_in[21];
  const float* bWs = (const float*)d_in[22];
  const float* bbs = (const float*)d_in[23];

  float* wsym   = (float*)d_ws;          // 5120
  float* sigma  = wsym + 5120;           // 1024
  float* hwg    = sigma + 1024;          // 744 (+pad)
  float* log_pi = hwg + 768;             // 1024*32
  float* atom_out = (float*)d_out;                    // 1024*400
  float* edge_out = atom_out + (size_t)1024 * 400;    // 1024*780*5

  prep_kernel<<<284, 256, 0, stream>>>(eta, cW1, cb1, cW2, cb2, cWs, cbs,
                                       bond, lsig, bW1, bb1, bW2, bb2, bWs, bbs,
                                       log_pi, wsym, sigma, hwg);
  fused_kernel<<<1024, 256, 0, stream>>>(log_pi, gumbel, z_noise,
                                         means, sigma, aW1, ab1, aW2, ab2, aWs, abs_,
                                         wsym, hwg, atom_out, edge_out);
}

// Round 13
// 171.570 us; speedup vs baseline: 1.0226x; 1.0226x over previous
//
#include <hip/hip_runtime.h>

constexpr int NPAIR = 780;

// ---- fused-kernel LDS layout (floats) ----
constexpr int OFF_ZT = 0;            // Zt[32][40] stride 40            1280
constexpr int OFF_A  = 1280;         // h[40][132]=5280 | Ut[3][32][40]=3840
constexpr int UTP    = 1280;         // Ut plane stride
constexpr int OFF_BT = 5120;         // bilT[5][780]=3900
constexpr int SH_TOT = 9020;         // 36080 B -> 4 blocks/CU

// ---- packed fp32 helpers (VOP3P). gfx950 packed-f32 set: fma/mul/add/mov ONLY
// (no packed max — use scalar v_max_f32 on halves).
// ISA rule: every pk source is a 64-bit register PAIR; op_sel picks halves.
typedef float v2f __attribute__((ext_vector_type(2)));
typedef float v4f __attribute__((ext_vector_type(4)));
union V4 { v4f v; v2f h[2]; float f[4]; };

// acc.k += s2.lo * b.k  (broadcast LOW half of s2)   [bit-exact 2xFMA]
__device__ __forceinline__ void pk_fma_lo(v2f& acc, v2f s2, v2f b) {
  asm("v_pk_fma_f32 %0, %1, %2, %0 op_sel:[0,0,0] op_sel_hi:[0,1,1]"
      : "+v"(acc) : "v"(s2), "v"(b));
}
// acc.k += s2.hi * b.k  (broadcast HIGH half of s2)
__device__ __forceinline__ void pk_fma_hi(v2f& acc, v2f s2, v2f b) {
  asm("v_pk_fma_f32 %0, %1, %2, %0 op_sel:[1,0,0] op_sel_hi:[1,1,1]"
      : "+v"(acc) : "v"(s2), "v"(b));
}
// acc.k += a.k * b.k, b from SGPR pair (uniform weights)
__device__ __forceinline__ void pk_fma_vs(v2f& acc, v2f a, v2f b) {
  asm("v_pk_fma_f32 %0, %1, %2, %0 op_sel:[0,0,0] op_sel_hi:[1,1,1]"
      : "+v"(acc) : "v"(a), "s"(b));
}
__device__ __forceinline__ v2f pk_add(v2f a, v2f b) {
  v2f d; asm("v_pk_add_f32 %0, %1, %2" : "=v"(d) : "v"(a), "v"(b)); return d;
}
// relu(a+b) with scalar maxes (no packed max on gfx950)
__device__ __forceinline__ v2f pk_addrelu(v2f a, v2f b) {
  v2f s = pk_add(a, b);
  v2f d; d.x = fmaxf(s.x, 0.f); d.y = fmaxf(s.y, 0.f);
  return d;
}

// =================== prep: cluster head + wsym + sigma + head-weight table ===================
__global__ __launch_bounds__(256) void prep_kernel(
    const float* __restrict__ eta,
    const float* __restrict__ cW1, const float* __restrict__ cb1,
    const float* __restrict__ cW2, const float* __restrict__ cb2,
    const float* __restrict__ cWs, const float* __restrict__ cbs,
    const float* __restrict__ bond, const float* __restrict__ lsig,
    const float* __restrict__ bW1, const float* __restrict__ bb1,
    const float* __restrict__ bW2, const float* __restrict__ bb2,
    const float* __restrict__ bWs, const float* __restrict__ bbs,
    float* __restrict__ log_pi, float* __restrict__ wsym,
    float* __restrict__ sigma, float* __restrict__ hwg)
{
  if (blockIdx.x < 256) {
    const int lane = threadIdx.x & 63, wid = threadIdx.x >> 6;
    const int row = blockIdx.x * 4 + wid;
    __shared__ __align__(16) float etas[4][64];
    __shared__ __align__(16) float hs[4][128];
    etas[wid][lane] = eta[row * 64 + lane];
    __syncthreads();
    float a0 = cb1[lane], a1 = cb1[lane + 64];
    for (int d = 0; d < 64; ++d) {
      float ed = etas[wid][d];
      a0 += ed * cW1[d * 128 + lane];
      a1 += ed * cW1[d * 128 + lane + 64];
    }
    hs[wid][lane] = fmaxf(a0, 0.f);
    hs[wid][lane + 64] = fmaxf(a1, 0.f);
    __syncthreads();
    if (lane < 32) {
      float x = cb2[lane] + cbs[lane];
      for (int j = 0; j < 128; ++j) x += hs[wid][j] * cW2[j * 32 + lane];
      for (int d = 0; d < 64; ++d) x += etas[wid][d] * cWs[d * 32 + lane];
      float m = x;
      for (int off = 16; off; off >>= 1) m = fmaxf(m, __shfl_xor(m, off));
      float e = __expf(x - m);
      float s = e;
      for (int off = 16; off; off >>= 1) s += __shfl_xor(s, off);
      log_pi[row * 32 + lane] = (x - m) - __logf(s);
    }
  } else {
    const int e = (blockIdx.x - 256) * 256 + threadIdx.x;
    if (e < 5120) {
      const int t = e >> 10, r = e & 1023, c = r >> 5, d = r & 31;
      wsym[e] = 0.5f * (bond[e] + bond[t * 1024 + d * 32 + c]);
    } else if (e < 6144) {
      const int q = e - 5120;
      sigma[q] = __expf(fminf(fmaxf(lsig[q], -20.f), 30.f));
    } else if (e < 6888) {
      // hwg: w1h[320]@0, b1h[64]@320, w2t[320]@384 (bW2^T), b2h[5]@704, wsh[25]@709, bsh[5]@734
      const int idx = e - 6144;
      float v;
      if (idx < 320) v = bW1[idx];
      else if (idx < 384) v = bb1[idx - 320];
      else if (idx < 704) { int qq = idx - 384; int t2 = qq >> 6, j = qq & 63; v = bW2[j * 5 + t2]; }
      else if (idx < 709) v = bb2[idx - 704];
      else if (idx < 734) v = bWs[idx - 709];
      else v = bbs[idx - 734];
      hwg[idx] = v;
    }
  }
}

// =================== fused per-molecule kernel, 256 threads ===================
// R20 = R12 (best known: R6 + tail-wave rotation + P1 hoist)
//   + s_setprio(1) around the three dense pk-FMA clusters (P2/P4/P5).
// Mechanism (T5): 4 co-resident blocks are independent and drift across phases;
// priority lets FMA-phase waves win issue arbitration over epilogue/load-phase
// waves on the same SIMD. Zero math change — bit-exact vs R12.
__global__ __launch_bounds__(256, 4) void fused_kernel(
    const float* __restrict__ log_pi, const float* __restrict__ gumbel,
    const float* __restrict__ z_noise,
    const float* __restrict__ means, const float* __restrict__ sigma,
    const float* __restrict__ aW1, const float* __restrict__ ab1,
    const float* __restrict__ aW2, const float* __restrict__ ab2,
    const float* __restrict__ aWs, const float* __restrict__ abs_,
    const float* __restrict__ wsym, const float* __restrict__ hwg,
    float* __restrict__ atom_out, float* __restrict__ edge_out)
{
  __shared__ __align__(16) float S[SH_TOT];
  const int tid = threadIdx.x;
  const int lane = tid & 63, wid = tid >> 6;
  const int m = blockIdx.x;

  // ---------- phase 1: z sample, 40n x 4sub = 160 threads spread over all waves ----------
  if (lane < 40) {
    const int n = wid * 10 + (lane >> 2);     // 10 nodes per wave
    const int sub = lane & 3;                 // 4 lanes cooperate per node
    const int c0 = sub * 8;                   // 8 channels each
    const int n_glb = m * 40 + n;
    const float4* lp4 = (const float4*)(log_pi + m * 32 + c0);
    const float4* g4  = (const float4*)(gumbel + (size_t)n_glb * 32 + c0);
    const float4* zn4 = (const float4*)(z_noise + (size_t)n_glb * 32 + c0);
    float4 zn0 = zn4[0], zn1 = zn4[1];        // hoisted: independent of argmax
    float vals[8];
    {
      float4 a = lp4[0], b = g4[0];
      vals[0] = a.x + b.x; vals[1] = a.y + b.y; vals[2] = a.z + b.z; vals[3] = a.w + b.w;
    }
    {
      float4 a = lp4[1], b = g4[1];
      vals[4] = a.x + b.x; vals[5] = a.y + b.y; vals[6] = a.z + b.z; vals[7] = a.w + b.w;
    }
    int kb = c0; float vb = vals[0];
    #pragma unroll
    for (int q = 1; q < 8; ++q)
      if (vals[q] > vb) { vb = vals[q]; kb = c0 + q; }   // first-index within thread
    // 4-lane argmax reduce, first-index tie-break (smaller channel wins on equal value)
    #pragma unroll
    for (int off = 1; off <= 2; off <<= 1) {
      float vo = __shfl_xor(vb, off);
      int   ko = __shfl_xor(kb, off);
      if (vo > vb || (vo == vb && ko < kb)) { vb = vo; kb = ko; }
    }
    const float4* mk4 = (const float4*)(means + kb * 32 + c0);
    const float4* sg4 = (const float4*)(sigma + kb * 32 + c0);
    {
      float4 mk = mk4[0], sg = sg4[0];
      S[OFF_ZT + (c0    ) * 40 + n] = zn0.x * sg.x + mk.x;
      S[OFF_ZT + (c0 + 1) * 40 + n] = zn0.y * sg.y + mk.y;
      S[OFF_ZT + (c0 + 2) * 40 + n] = zn0.z * sg.z + mk.z;
      S[OFF_ZT + (c0 + 3) * 40 + n] = zn0.w * sg.w + mk.w;
    }
    {
      float4 mk = mk4[1], sg = sg4[1];
      S[OFF_ZT + (c0 + 4) * 40 + n] = zn1.x * sg.x + mk.x;
      S[OFF_ZT + (c0 + 5) * 40 + n] = zn1.y * sg.y + mk.y;
      S[OFF_ZT + (c0 + 6) * 40 + n] = zn1.z * sg.z + mk.z;
      S[OFF_ZT + (c0 + 7) * 40 + n] = zn1.w * sg.w + mk.w;
    }
  }
  __syncthreads();

  // ---------- phase 2: atom-h, 4n x 4j tiles -> h[n][j] row-major (stride 132) ----------
  {
    for (int u = tid; u < 320; u += 256) {
      const int ng = u >> 5, jg = u & 31;
      const int n0 = ng * 4, j0 = jg * 4;
      v2f acc[4][2];
      #pragma unroll
      for (int a = 0; a < 4; ++a) { acc[a][0] = (v2f){0.f,0.f}; acc[a][1] = (v2f){0.f,0.f}; }
      __builtin_amdgcn_s_setprio(1);
      #pragma unroll 8
      for (int c = 0; c < 32; ++c) {
        V4 zv; zv.v = *(const v4f*)&S[OFF_ZT + c * 40 + n0];
        V4 wv; wv.v = *(const v4f*)(aW1 + c * 128 + j0);
        pk_fma_lo(acc[0][0], zv.h[0], wv.h[0]); pk_fma_lo(acc[0][1], zv.h[0], wv.h[1]);
        pk_fma_hi(acc[1][0], zv.h[0], wv.h[0]); pk_fma_hi(acc[1][1], zv.h[0], wv.h[1]);
        pk_fma_lo(acc[2][0], zv.h[1], wv.h[0]); pk_fma_lo(acc[2][1], zv.h[1], wv.h[1]);
        pk_fma_hi(acc[3][0], zv.h[1], wv.h[0]); pk_fma_hi(acc[3][1], zv.h[1], wv.h[1]);
      }
      __builtin_amdgcn_s_setprio(0);
      V4 bv; bv.v = *(const v4f*)(ab1 + j0);
      #pragma unroll
      for (int a = 0; a < 4; ++a) {
        V4 hv;
        hv.h[0] = pk_addrelu(acc[a][0], bv.h[0]);
        hv.h[1] = pk_addrelu(acc[a][1], bv.h[1]);
        *(v4f*)&S[OFF_A + (n0 + a) * 132 + j0] = hv.v;   // unit-stride b128 writes
      }
    }
  }
  __syncthreads();

  // ---------- phase 3: atom-out, thread = (n, kpair) ----------
  if (tid < 200) {
    const int n = tid / 5, kp = tid - (tid / 5) * 5, k0 = kp * 2;
    float a0 = ab2[k0] + abs_[k0];
    float a1 = ab2[k0 + 1] + abs_[k0 + 1];
    #pragma unroll 8
    for (int c = 0; c < 32; ++c) {
      float zc = S[OFF_ZT + c * 40 + n];
      float2 w = *(const float2*)(aWs + c * 10 + k0);
      a0 += zc * w.x; a1 += zc * w.y;
    }
    #pragma unroll 8
    for (int j = 0; j < 128; ++j) {
      float hv = S[OFF_A + n * 132 + j];
      float2 w = *(const float2*)(aW2 + j * 10 + k0);
      a0 += hv * w.x; a1 += hv * w.y;
    }
    *(float2*)(atom_out + (size_t)m * 400 + n * 10 + k0) = make_float2(a0, a1);
  }
  __syncthreads();   // h dead

  // ---------- phases 4-7: U + bilinear, two t-rounds ----------
  #pragma unroll
  for (int R = 0; R < 2; ++R) {
    const int tbase = (R == 0) ? 0 : 3;
    const int nplanes = (R == 0) ? 3 : 2;
    // U: units (tl, dg, ig) -> Ut[tl][d][i]
    if (tid < nplanes * 80) {
      const int tl = tid / 80, r = tid - tl * 80;
      const int dg = r / 10, ig = r - dg * 10;
      const int d0 = dg * 4, i0 = ig * 4;
      const float* wg = wsym + (tbase + tl) * 1024;
      v2f acc[4][2];   // [di][pair of i]
      #pragma unroll
      for (int a = 0; a < 4; ++a) { acc[a][0] = (v2f){0.f,0.f}; acc[a][1] = (v2f){0.f,0.f}; }
      __builtin_amdgcn_s_setprio(1);
      #pragma unroll 8
      for (int c = 0; c < 32; ++c) {
        V4 zv; zv.v = *(const v4f*)&S[OFF_ZT + c * 40 + i0];
        V4 wv; wv.v = *(const v4f*)(wg + c * 32 + d0);
        pk_fma_lo(acc[0][0], wv.h[0], zv.h[0]); pk_fma_lo(acc[0][1], wv.h[0], zv.h[1]);
        pk_fma_hi(acc[1][0], wv.h[0], zv.h[0]); pk_fma_hi(acc[1][1], wv.h[0], zv.h[1]);
        pk_fma_lo(acc[2][0], wv.h[1], zv.h[0]); pk_fma_lo(acc[2][1], wv.h[1], zv.h[1]);
        pk_fma_hi(acc[3][0], wv.h[1], zv.h[0]); pk_fma_hi(acc[3][1], wv.h[1], zv.h[1]);
      }
      __builtin_amdgcn_s_setprio(0);
      #pragma unroll
      for (int a = 0; a < 4; ++a) {
        V4 st; st.h[0] = acc[a][0]; st.h[1] = acc[a][1];
        *(v4f*)&S[OFF_A + tl * UTP + (d0 + a) * 40 + i0] = st.v;
      }
    }
    __syncthreads();

    // bilinear: units (tl, triangular 4i x 4j tile)
    if (tid < nplanes * 55) {
      const int tl = tid / 55;
      int q = tid - tl * 55;
      int ig = 0;
      while (q >= 10 - ig) { q -= 10 - ig; ++ig; }
      const int jg = ig + q;
      const int i0 = ig * 4, j0 = jg * 4;
      v2f acc[4][2];   // [i][pair of j]
      #pragma unroll
      for (int a = 0; a < 4; ++a) { acc[a][0] = (v2f){0.f,0.f}; acc[a][1] = (v2f){0.f,0.f}; }
      __builtin_amdgcn_s_setprio(1);
      #pragma unroll 8
      for (int d = 0; d < 32; ++d) {
        V4 uv; uv.v = *(const v4f*)&S[OFF_A + tl * UTP + d * 40 + i0];
        V4 zv; zv.v = *(const v4f*)&S[OFF_ZT + d * 40 + j0];
        pk_fma_lo(acc[0][0], uv.h[0], zv.h[0]); pk_fma_lo(acc[0][1], uv.h[0], zv.h[1]);
        pk_fma_hi(acc[1][0], uv.h[0], zv.h[0]); pk_fma_hi(acc[1][1], uv.h[0], zv.h[1]);
        pk_fma_lo(acc[2][0], uv.h[1], zv.h[0]); pk_fma_lo(acc[2][1], uv.h[1], zv.h[1]);
        pk_fma_hi(acc[3][0], uv.h[1], zv.h[0]); pk_fma_hi(acc[3][1], uv.h[1], zv.h[1]);
      }
      __builtin_amdgcn_s_setprio(0);
      const int tg = tbase + tl;
      #pragma unroll
      for (int a = 0; a < 4; ++a) {
        const int i = i0 + a;
        V4 row; row.h[0] = acc[a][0]; row.h[1] = acc[a][1];
        #pragma unroll
        for (int b = 0; b < 4; ++b) {
          const int j = j0 + b;
          if (i < j) {
            const int p = i * (79 - i) / 2 + (j - i - 1);
            S[OFF_BT + tg * 780 + p] = row.f[b];
          }
        }
      }
    }
    __syncthreads();
  }

  // ---------- phase 8: edge head; weights via UNIFORM global loads (s_load) ----------
  const float* w1h = hwg;
  const float* b1h = hwg + 320;
  const float* w2t = hwg + 384;
  const float* b2h = hwg + 704;
  const float* wsh = hwg + 709;
  const float* bsh = hwg + 734;

  // main: 3 unconditional slots (pairs 0..767) + guarded tail slot (768..779)
  // tail wave rotates with (m>>8)&3 so co-resident blocks' tails hit different SIMDs
  const bool htail = (wid == ((m >> 8) & 3)) && (lane < 12);
  const int ptail = 768 + lane;
  float bil5[3][5];
  v2f bil2[3][5];   // {v,v} broadcast pairs for pk src0
  v2f lg2[3][5];    // packed partial sums; .x seeded with the skip path
  #pragma unroll
  for (int s = 0; s < 3; ++s) {
    const int p = tid + (s << 8);
    #pragma unroll
    for (int t = 0; t < 5; ++t) {
      float v = S[OFF_BT + t * 780 + p];
      bil5[s][t] = v;
      bil2[s][t].x = v; bil2[s][t].y = v;
    }
    #pragma unroll
    for (int t2 = 0; t2 < 5; ++t2) {
      float a = b2h[t2] + bsh[t2];
      #pragma unroll
      for (int t = 0; t < 5; ++t) a += bil5[s][t] * wsh[t * 5 + t2];
      lg2[s][t2].x = a; lg2[s][t2].y = 0.f;
    }
  }
  float bil3[5], lg3[5];
  if (htail) {
    #pragma unroll
    for (int t = 0; t < 5; ++t) bil3[t] = S[OFF_BT + t * 780 + ptail];
    #pragma unroll
    for (int t2 = 0; t2 < 5; ++t2) {
      float a = b2h[t2] + bsh[t2];
      #pragma unroll
      for (int t = 0; t < 5; ++t) a += bil3[t] * wsh[t * 5 + t2];
      lg3[t2] = a;
    }
  }
  {
    for (int j4 = 0; j4 < 16; ++j4) {
      V4 bb; bb.v = *(const v4f*)(b1h + 4 * j4);       // uniform -> SGPR
      v2f h2[3][2];
      #pragma unroll
      for (int s = 0; s < 3; ++s) { h2[s][0] = bb.h[0]; h2[s][1] = bb.h[1]; }
      #pragma unroll
      for (int t = 0; t < 5; ++t) {
        V4 w1; w1.v = *(const v4f*)(w1h + t * 64 + 4 * j4);  // uniform -> SGPR
        #pragma unroll
        for (int s = 0; s < 3; ++s) {
          pk_fma_vs(h2[s][0], bil2[s][t], w1.h[0]);
          pk_fma_vs(h2[s][1], bil2[s][t], w1.h[1]);
        }
      }
      #pragma unroll
      for (int s = 0; s < 3; ++s) {
        h2[s][0].x = fmaxf(h2[s][0].x, 0.f); h2[s][0].y = fmaxf(h2[s][0].y, 0.f);
        h2[s][1].x = fmaxf(h2[s][1].x, 0.f); h2[s][1].y = fmaxf(h2[s][1].y, 0.f);
      }
      #pragma unroll
      for (int t2 = 0; t2 < 5; ++t2) {
        V4 w2; w2.v = *(const v4f*)(w2t + t2 * 64 + 4 * j4); // uniform -> SGPR
        #pragma unroll
        for (int s = 0; s < 3; ++s) {
          pk_fma_vs(lg2[s][t2], h2[s][0], w2.h[0]);
          pk_fma_vs(lg2[s][t2], h2[s][1], w2.h[1]);
        }
      }
      // tail slot: only the designated wave's lanes 0..11 enter (execz-skip elsewhere)
      if (htail) {
        float4 h3 = make_float4(bb.f[0], bb.f[1], bb.f[2], bb.f[3]);
        #pragma unroll
        for (int t = 0; t < 5; ++t) {
          const float* w1p = w1h + t * 64 + 4 * j4;
          float bt = bil3[t];
          h3.x += bt * w1p[0]; h3.y += bt * w1p[1]; h3.z += bt * w1p[2]; h3.w += bt * w1p[3];
        }
        h3.x = fmaxf(h3.x, 0.f); h3.y = fmaxf(h3.y, 0.f);
        h3.z = fmaxf(h3.z, 0.f); h3.w = fmaxf(h3.w, 0.f);
        #pragma unroll
        for (int t2 = 0; t2 < 5; ++t2) {
          const float* w2p = w2t + t2 * 64 + 4 * j4;
          lg3[t2] += h3.x * w2p[0] + h3.y * w2p[1] + h3.z * w2p[2] + h3.w * w2p[3];
        }
      }
    }
  }
  #pragma unroll
  for (int s = 0; s < 3; ++s) {
    const int p = tid + (s << 8);
    float lgv[5];
    #pragma unroll
    for (int t2 = 0; t2 < 5; ++t2) lgv[t2] = lg2[s][t2].x + lg2[s][t2].y;
    float mx = lgv[0];
    #pragma unroll
    for (int t2 = 1; t2 < 5; ++t2) mx = fmaxf(mx, lgv[t2]);
    float e[5], sum = 0.f;
    #pragma unroll
    for (int t2 = 0; t2 < 5; ++t2) { e[t2] = __expf(lgv[t2] - mx); sum += e[t2]; }
    float inv = 1.f / sum;
    float* outp = edge_out + ((size_t)m * NPAIR + p) * 5;
    #pragma unroll
    for (int t2 = 0; t2 < 5; ++t2) outp[t2] = e[t2] * inv;
  }
  if (htail) {
    float mx = lg3[0];
    #pragma unroll
    for (int t2 = 1; t2 < 5; ++t2) mx = fmaxf(mx, lg3[t2]);
    float e[5], sum = 0.f;
    #pragma unroll
    for (int t2 = 0; t2 < 5; ++t2) { e[t2] = __expf(lg3[t2] - mx); sum += e[t2]; }
    float inv = 1.f / sum;
    float* outp = edge_out + ((size_t)m * NPAIR + ptail) * 5;
    #pragma unroll
    for (int t2 = 0; t2 < 5; ++t2) outp[t2] = e[t2] * inv;
  }
}

extern "C" void kernel_launch(void* const* d_in, const int* in_sizes, int n_in,
                              void* d_out, int out_size, void* d_ws, size_t ws_size,
                              hipStream_t stream) {
  const float* eta    = (const float*)d_in[0];
  const float* gumbel = (const float*)d_in[1];
  const float* z_noise= (const float*)d_in[2];
  const float* cW1 = (const float*)d_in[3];
  const float* cb1 = (const float*)d_in[4];
  const float* cW2 = (const float*)d_in[5];
  const float* cb2 = (const float*)d_in[6];
  const float* cWs = (const float*)d_in[7];
  const float* cbs = (const float*)d_in[8];
  const float* means = (const float*)d_in[9];
  const float* lsig  = (const float*)d_in[10];
  const float* aW1 = (const float*)d_in[11];
  const float* ab1 = (const float*)d_in[12];
  const float* aW2 = (const float*)d_in[13];
  const float* ab2 = (const float*)d_in[14];
  const float* aWs = (const float*)d_in[15];
  const float* abs_= (const float*)d_in[16];
  const float* bond= (const float*)d_in[17];
  const float* bW1 = (const float*)d_in[18];
  const float* bb1 = (const float*)d_in[19];
  const float* bW2 = (const float*)d_in[20];
  const float* bb2 = (const float*)d_in[21];
  const float* bWs = (const float*)d_in[22];
  const float* bbs = (const float*)d_in[23];

  float* wsym   = (float*)d_ws;          // 5120
  float* sigma  = wsym + 5120;           // 1024
  float* hwg    = sigma + 1024;          // 744 (+pad)
  float* log_pi = hwg + 768;             // 1024*32
  float* atom_out = (float*)d_out;                    // 1024*400
  float* edge_out = atom_out + (size_t)1024 * 400;    // 1024*780*5

  prep_kernel<<<284, 256, 0, stream>>>(eta, cW1, cb1, cW2, cb2, cWs, cbs,
                                       bond, lsig, bW1, bb1, bW2, bb2, bWs, bbs,
                                       log_pi, wsym, sigma, hwg);
  fused_kernel<<<1024, 256, 0, stream>>>(log_pi, gumbel, z_noise,
                                         means, sigma, aW1, ab1, aW2, ab2, aWs, abs_,
                                         wsym, hwg, atom_out, edge_out);
}